// Round 17
// baseline (157.764 us; speedup 1.0000x reference)
//
#include <hip/hip_runtime.h>
#include <hip/hip_cooperative_groups.h>

#define DDIM    128
#define NS      4           // column slices per relation
#define SG      2           // sample groups per (relation, slice)
#define SCOL    32          // output columns per block
#define SCH     10          // samples per compute chunk (30 rows <= MROWS)
#define MROWS   32
#define XSTRIDE 136         // bf16 row stride in LDS (conflict-free b128)
#define SEGCAP  64          // per-wave scan match cap (1024 cand, mean 5.1)
#define BSTRIDE 128         // list slots per relation (P(cnt>128) ~ 0)
#define GRID    1024        // must be <= co-resident capacity (4 blocks/CU)

typedef __attribute__((ext_vector_type(8))) short bf16x8;
typedef __attribute__((ext_vector_type(4))) float f32x4;

static __device__ inline unsigned short f2b(float f) {
    unsigned u = __float_as_uint(f);
    u += 0x7fff + ((u >> 16) & 1);      // round-to-nearest-even
    return (unsigned short)(u >> 16);
}

__global__ __launch_bounds__(256, 4) void transr_coop(
    const int* __restrict__ h, const int* __restrict__ r,
    const int* __restrict__ pos_t, const int* __restrict__ neg_t,
    const float* __restrict__ ent, const float* __restrict__ rel,
    const float* __restrict__ M, float* __restrict__ out,
    unsigned short* __restrict__ Xp,      // [3*B][128] bf16
    unsigned short* __restrict__ Wtp,     // [R][16 kg][128 n][8] bf16 frags
    int* __restrict__ cntg, int* __restrict__ listg,
    int B, int R)
{
    const int bid  = blockIdx.x;
    const int t    = threadIdx.x;
    const int wvid = t >> 6;
    const int ln   = t & 63;
    const int gt   = bid * 256 + t;
    const int GT   = GRID * 256;

    __shared__ __align__(16) unsigned short Xl[MROWS * XSTRIDE];   // 8.5 KB
    __shared__ int seg[4][SEGCAP];
    __shared__ int wcnt[4];
    __shared__ int ssid[SCH];

    // ================= PHASE 1 (streaming, no intra-block barriers) ========
    // 1a: pack gathered X rows to bf16 (scatter-read ent ONCE)
    for (int u = gt; u < 3 * B * 16; u += GT) {
        const int row = u >> 4;
        const int kg  = u & 15;
        const int i   = row / 3;
        const int v   = row - 3 * i;
        const int eid = (v == 0) ? h[i] : (v == 1) ? pos_t[i] : neg_t[i];
        const float4 a = *(const float4*)(ent + (size_t)eid * DDIM + kg * 8);
        const float4 b = *(const float4*)(ent + (size_t)eid * DDIM + kg * 8 + 4);
        bf16x8 x;
        x[0] = (short)f2b(a.x); x[1] = (short)f2b(a.y);
        x[2] = (short)f2b(a.z); x[3] = (short)f2b(a.w);
        x[4] = (short)f2b(b.x); x[5] = (short)f2b(b.y);
        x[6] = (short)f2b(b.z); x[7] = (short)f2b(b.w);
        *(bf16x8*)(Xp + (size_t)row * DDIM + kg * 8) = x;
    }

    // 1b: pack W^T bf16 frags (M read ONCE; lanes n-consecutive -> coalesced)
    for (int u = gt; u < R * 2048; u += GT) {
        const int rl   = u >> 11;
        const int rest = u & 2047;
        const int kg   = rest >> 7;
        const int n    = rest & 127;
        const float* __restrict__ Wg = M + (size_t)rl * DDIM * DDIM + n;
        bf16x8 w;
        #pragma unroll
        for (int j = 0; j < 8; ++j)
            w[j] = (short)f2b(Wg[(size_t)(kg * 8 + j) * DDIM]);
        *(bf16x8*)(Wtp + (size_t)rl * 16384 + kg * 1024 + n * 8) = w;
    }

    // 1c: r_e output (pure gather copy)
    for (int u = gt; u < B * 32; u += GT) {
        const int i  = u >> 5;
        const int c4 = u & 31;
        const int rr = r[i];
        const float4 v = *(const float4*)(rel + (size_t)rr * DDIM + c4 * 4);
        *(float4*)(out + (size_t)B * DDIM + (size_t)i * DDIM + c4 * 4) = v;
    }

    // 1d: relation scans (blocks 0..R-1), lists to workspace
    if (bid < R) {
        const int rb = bid;
        int segn = 0;
        const int qlen4  = B >> 4;
        const int qbase4 = wvid * qlen4;
        const int4* __restrict__ r4 = (const int4*)r;
        for (int i0 = 0; i0 < qlen4; i0 += 64) {
            const int  e4 = qbase4 + i0 + ln;
            const int4 rv = r4[e4];
            const int  ib = e4 << 2;
            #pragma unroll
            for (int j = 0; j < 4; ++j) {
                const int  rj = (j == 0) ? rv.x : (j == 1) ? rv.y : (j == 2) ? rv.z : rv.w;
                const bool f  = (rj == rb);
                const unsigned long long m = __ballot(f);
                if (f) {
                    const int p = segn + __popcll(m & ((1ull << ln) - 1ull));
                    if (p < SEGCAP) seg[wvid][p] = ib + j;
                }
                segn += __popcll(m);
            }
        }
        if (ln == 0) wcnt[wvid] = min(segn, SEGCAP);
        __syncthreads();
        const int c0 = wcnt[0], c1 = wcnt[1], c2 = wcnt[2], c3 = wcnt[3];
        const int cum1 = c0, cum2 = c0 + c1, cum3 = c0 + c1 + c2;
        const int cnt  = min(cum3 + c3, BSTRIDE);
        for (int lin = t; lin < cnt; lin += 256) {
            int w, k;
            if      (lin < cum1) { w = 0; k = lin;        }
            else if (lin < cum2) { w = 1; k = lin - cum1; }
            else if (lin < cum3) { w = 2; k = lin - cum2; }
            else                 { w = 3; k = lin - cum3; }
            listg[rb * BSTRIDE + lin] = seg[w][k];
        }
        if (t == 0) cntg[rb] = cnt;
    }

    cooperative_groups::this_grid().sync();

    // ================= PHASE 2 (1600 light consumer items) =================
    const int lr = ln & 15;
    const int lg = ln >> 4;
    const int mt = wvid & 1;
    const int nt = wvid >> 1;
    const size_t BD = (size_t)B * DDIM;

    for (int item = bid; item < R * NS * SG; item += GRID) {
        const int rb   = item % R;
        const int rest = item / R;
        const int qc   = rest & (NS - 1);
        const int sg   = rest >> 2;

        const int cnt = cntg[rb];
        if (cnt == 0) continue;
        const int halfc  = (cnt + 1) >> 1;
        const int gstart = sg * halfc;
        const int gcnt   = max(0, min(cnt - gstart, halfc));
        if (gcnt == 0) continue;
        const int* __restrict__ lst = listg + rb * BSTRIDE + gstart;

        // B fragments straight from packed global (L3-hot, coalesced)
        const unsigned short* __restrict__ Wb =
            Wtp + (size_t)rb * 16384 + (qc * SCOL + nt * 16 + lr) * 8;
        bf16x8 bfr[4];
        #pragma unroll
        for (int ks = 0; ks < 4; ++ks)
            bfr[ks] = *(const bf16x8*)(Wb + (ks * 4 + lg) * 1024);

        for (int ch = 0; ch < gcnt; ch += SCH) {
            const int ccnt = min(SCH, gcnt - ch);
            const int rows_valid = 3 * ccnt;

            if (t < ccnt) ssid[t] = lst[ch + t];
            // stage from packed bf16: ONE 16-B load per fragment
            for (int lin = t; lin < rows_valid * 16; lin += 256) {
                const int row  = lin >> 4;
                const int kg   = lin & 15;
                const int jj   = row / 3;
                const int v    = row - 3 * jj;
                const int sidx = lst[ch + jj];
                const bf16x8 x = *(const bf16x8*)(Xp + ((size_t)sidx * 3 + v) * DDIM + kg * 8);
                *(bf16x8*)(&Xl[row * XSTRIDE + kg * 8]) = x;
            }
            __syncthreads();

            f32x4 acc = {0.f, 0.f, 0.f, 0.f};
            #pragma unroll
            for (int ks = 0; ks < 4; ++ks) {
                const int kg = ks * 4 + lg;
                const bf16x8 a = *(const bf16x8*)(&Xl[(mt * 16 + lr) * XSTRIDE + kg * 8]);
                acc = __builtin_amdgcn_mfma_f32_16x16x32_bf16(a, bfr[ks], acc, 0, 0, 0);
            }

            // epilogue: C layout col=lane&15, row=(lane>>4)*4+reg
            #pragma unroll
            for (int q = 0; q < 4; ++q) {
                const int rowe = mt * 16 + lg * 4 + q;
                if (rowe < rows_valid) {
                    const int jj = rowe / 3;
                    const int v2 = rowe - 3 * jj;
                    const size_t s = (size_t)ssid[jj];
                    float* bp = (v2 == 0) ? out : (v2 == 1) ? (out + 2 * BD) : (out + 3 * BD);
                    bp[s * DDIM + qc * SCOL + nt * 16 + lr] = acc[q];
                }
            }
            __syncthreads();   // protect Xl/ssid before next chunk/item
        }
    }
}

extern "C" void kernel_launch(void* const* d_in, const int* in_sizes, int n_in,
                              void* d_out, int out_size, void* d_ws, size_t ws_size,
                              hipStream_t stream) {
    const int*   h     = (const int*)d_in[0];
    const int*   r     = (const int*)d_in[1];
    const int*   pos_t = (const int*)d_in[2];
    const int*   neg_t = (const int*)d_in[3];
    const float* ent   = (const float*)d_in[4];
    const float* rel   = (const float*)d_in[5];
    const float* M     = (const float*)d_in[6];
    float*       out   = (float*)d_out;

    int B = in_sizes[0];
    int R = in_sizes[5] / DDIM;

    unsigned short* Xp  = (unsigned short*)d_ws;              // 3*B*128 bf16
    unsigned short* Wtp = Xp + (size_t)3 * B * DDIM;          // R*16384 bf16
    int* cntg  = (int*)(Wtp + (size_t)R * DDIM * DDIM);       // [R]
    int* listg = cntg + R;                                    // [R*BSTRIDE]

    void* args[] = { &h, &r, &pos_t, &neg_t, &ent, &rel, &M, &out,
                     &Xp, &Wtp, &cntg, &listg, &B, &R };
    hipLaunchCooperativeKernel((void*)transr_coop, dim3(GRID), dim3(256),
                               args, 0, stream);
}

// Round 18
// 14.461 us; speedup vs baseline: 10.9098x; 10.9098x over previous
//
#include <hip/hip_runtime.h>

#define DDIM    128
#define NS      4           // column slices per relation
#define SG      2           // r-halves per (relation, slice)
#define SCOL    32          // output columns per block
#define SCH     10          // samples per compute chunk (30 rows <= MROWS)
#define MROWS   32
#define XSTRIDE 136         // bf16 row stride (272B -> conflict-free b128)
#define WSTRIDE 136
#define SEGCAP  64          // per-wave match cap (512 cand, mean 2.6 -> P(>64)~0)

typedef __attribute__((ext_vector_type(8))) short bf16x8;
typedef __attribute__((ext_vector_type(4))) float f32x4;

static __device__ inline unsigned short f2b(float f) {
    unsigned u = __float_as_uint(f);
    u += 0x7fff + ((u >> 16) & 1);      // round-to-nearest-even
    return (unsigned short)(u >> 16);
}

__global__ __launch_bounds__(256) void transr_mfma(
    const int* __restrict__ h, const int* __restrict__ r,
    const int* __restrict__ pos_t, const int* __restrict__ neg_t,
    const float* __restrict__ ent, const float* __restrict__ rel,
    const float* __restrict__ M, float* __restrict__ out,
    int B, int R)
{
    const int bid  = blockIdx.x;
    const int rb   = bid % R;          // R%8==0: all blocks of rb share an XCD
    const int rest = bid / R;
    const int qc   = rest & (NS - 1);  // 0..3 column slice
    const int sg   = rest >> 2;        // 0..1 r-half
    const int t    = threadIdx.x;
    const int wvid = t >> 6;
    const int ln   = t & 63;

    __shared__ __align__(16) unsigned short Xl[MROWS * XSTRIDE];   // 8.5 KB
    __shared__ __align__(16) unsigned short Wt[SCOL  * WSTRIDE];   // 8.5 KB
    __shared__ int seg[4][SEGCAP];
    __shared__ int wcnt[4];
    __shared__ int list_s[4 * SEGCAP];
    __shared__ int eid_s[3 * 4 * SEGCAP];

    // ---- issue W slice loads into REGISTERS (latency hides under scan) ----
    const int g  = t >> 4;             // 0..15 (k-group)
    const int nl = t & 15;             // 0..15 (local col)
    const float* __restrict__ Wg = M + (size_t)rb * DDIM * DDIM + qc * SCOL;
    float wreg0[8], wreg1[8];
    #pragma unroll
    for (int j = 0; j < 8; ++j) wreg0[j] = Wg[(size_t)(g * 8 + j) * DDIM + nl];
    #pragma unroll
    for (int j = 0; j < 8; ++j) wreg1[j] = Wg[(size_t)(g * 8 + j) * DDIM + nl + 16];

    // ---- per-wave int4 ballot scan of MY r-half only (2 rounds) ----
    int segn = 0;
    const int hlen4  = B >> 5;                       // int4 per wave quarter of my half
    const int qbase4 = ((sg * (B >> 1)) >> 2) + wvid * hlen4;
    const int4* __restrict__ r4 = (const int4*)r;
    for (int i0 = 0; i0 < hlen4; i0 += 64) {
        const int  e4 = qbase4 + i0 + ln;
        const int4 rv = r4[e4];
        const int  ib = e4 << 2;
        #pragma unroll
        for (int j = 0; j < 4; ++j) {
            const int  rj = (j == 0) ? rv.x : (j == 1) ? rv.y : (j == 2) ? rv.z : rv.w;
            const bool f  = (rj == rb);
            const unsigned long long m = __ballot(f);
            if (f) {
                const int p = segn + __popcll(m & ((1ull << ln) - 1ull));
                if (p < SEGCAP) seg[wvid][p] = ib + j;
            }
            segn += __popcll(m);
        }
    }
    if (ln == 0) wcnt[wvid] = min(segn, SEGCAP);

    // ---- convert W regs -> bf16 LDS (global loads landed under scan) ----
    {
        bf16x8 w0, w1;
        #pragma unroll
        for (int j = 0; j < 8; ++j) { w0[j] = (short)f2b(wreg0[j]); w1[j] = (short)f2b(wreg1[j]); }
        *(bf16x8*)(&Wt[nl * WSTRIDE + g * 8])        = w0;
        *(bf16x8*)(&Wt[(nl + 16) * WSTRIDE + g * 8]) = w1;
    }
    __syncthreads();

    const int c0 = wcnt[0], c1 = wcnt[1], c2 = wcnt[2], c3 = wcnt[3];
    const int cum1 = c0, cum2 = c0 + c1, cum3 = c0 + c1 + c2;
    const int cnt  = cum3 + c3;
    if (cnt == 0) return;

    // ---- compact list ----
    for (int lin = t; lin < cnt; lin += 256) {
        int w, k;
        if      (lin < cum1) { w = 0; k = lin;        }
        else if (lin < cum2) { w = 1; k = lin - cum1; }
        else if (lin < cum3) { w = 2; k = lin - cum2; }
        else                 { w = 3; k = lin - cum3; }
        list_s[lin] = seg[w][k];
    }
    // ---- wide eid prefetch in the SAME barrier region (seg-indexed) ----
    for (int i = t; i < 3 * cnt; i += 256) {
        const int jj = i / 3;
        const int v  = i - 3 * jj;
        int w, k;
        if      (jj < cum1) { w = 0; k = jj;        }
        else if (jj < cum2) { w = 1; k = jj - cum1; }
        else if (jj < cum3) { w = 2; k = jj - cum2; }
        else                { w = 3; k = jj - cum3; }
        const int sidx = seg[w][k];
        eid_s[i] = (v == 0) ? h[sidx] : (v == 1) ? pos_t[sidx] : neg_t[sidx];
    }
    __syncthreads();

    // ---- r_e gather: each block covers its own samples x its slice ----
    for (int lin = t; lin < cnt * (SCOL / 4); lin += 256) {
        const int j  = lin >> 3;
        const int c4 = lin & 7;
        const float4 v = *(const float4*)(rel + (size_t)rb * DDIM + qc * SCOL + c4 * 4);
        *(float4*)(out + (size_t)B * DDIM + (size_t)list_s[j] * DDIM + qc * SCOL + c4 * 4) = v;
    }

    // ---- hoist this wave's B fragments into registers ----
    const int lr = ln & 15;
    const int lg = ln >> 4;
    const int mt = wvid & 1;           // M-tile (rows mt*16..+15)
    const int nt = wvid >> 1;          // N-tile (cols nt*16..+15)
    bf16x8 bfr[4];
    #pragma unroll
    for (int ks = 0; ks < 4; ++ks) {
        const int kg = ks * 4 + lg;
        bfr[ks] = *(const bf16x8*)(&Wt[(nt * 16 + lr) * WSTRIDE + kg * 8]);
    }

    // ---- chunk loop over my samples (usually 1 iteration) ----
    const size_t BD = (size_t)B * DDIM;
    for (int ch = 0; ch < cnt; ch += SCH) {
        const int ccnt = min(SCH, cnt - ch);
        const int rows_valid = 3 * ccnt;
        const int rbase = 3 * ch;

        // stage the needed rows (<=30): 1-deep chain via eid_s
        for (int lin = t; lin < rows_valid * 16; lin += 256) {
            const int row  = lin >> 4;
            const int kg   = lin & 15;
            const int eid  = eid_s[rbase + row];
            const float4 a = *(const float4*)(ent + (size_t)eid * DDIM + kg * 8);
            const float4 b = *(const float4*)(ent + (size_t)eid * DDIM + kg * 8 + 4);
            bf16x8 x;
            x[0] = (short)f2b(a.x); x[1] = (short)f2b(a.y);
            x[2] = (short)f2b(a.z); x[3] = (short)f2b(a.w);
            x[4] = (short)f2b(b.x); x[5] = (short)f2b(b.y);
            x[6] = (short)f2b(b.z); x[7] = (short)f2b(b.w);
            *(bf16x8*)(&Xl[row * XSTRIDE + kg * 8]) = x;
        }
        __syncthreads();

        // MFMA: wave (mt,nt), 4 K-steps, B from regs
        f32x4 acc = {0.f, 0.f, 0.f, 0.f};
        #pragma unroll
        for (int ks = 0; ks < 4; ++ks) {
            const int kg = ks * 4 + lg;
            const bf16x8 a = *(const bf16x8*)(&Xl[(mt * 16 + lr) * XSTRIDE + kg * 8]);
            acc = __builtin_amdgcn_mfma_f32_16x16x32_bf16(a, bfr[ks], acc, 0, 0, 0);
        }

        // epilogue: C layout col=lane&15, row=(lane>>4)*4+reg
        #pragma unroll
        for (int q = 0; q < 4; ++q) {
            const int rowe = mt * 16 + lg * 4 + q;
            if (rowe < rows_valid) {
                const int jj = rowe / 3;
                const int v2 = rowe - 3 * jj;
                const size_t s = (size_t)list_s[ch + jj];
                float* bp = (v2 == 0) ? out : (v2 == 1) ? (out + 2 * BD) : (out + 3 * BD);
                bp[s * DDIM + qc * SCOL + nt * 16 + lr] = acc[q];
            }
        }
        __syncthreads();   // protect Xl before next chunk restage
    }
}

extern "C" void kernel_launch(void* const* d_in, const int* in_sizes, int n_in,
                              void* d_out, int out_size, void* d_ws, size_t ws_size,
                              hipStream_t stream) {
    const int*   h     = (const int*)d_in[0];
    const int*   r     = (const int*)d_in[1];
    const int*   pos_t = (const int*)d_in[2];
    const int*   neg_t = (const int*)d_in[3];
    const float* ent   = (const float*)d_in[4];
    const float* rel   = (const float*)d_in[5];
    const float* M     = (const float*)d_in[6];
    float*       out   = (float*)d_out;

    const int B = in_sizes[0];
    const int R = in_sizes[5] / DDIM;

    transr_mfma<<<dim3(R * NS * SG), dim3(256), 0, stream>>>(
        h, r, pos_t, neg_t, ent, rel, M, out, B, R);
}